// Round 17
// baseline (208.710 us; speedup 1.0000x reference)
//
#include <hip/hip_runtime.h>
#include <hip/hip_bf16.h>
#include <hip/hip_cooperative_groups.h>
#include <math.h>

namespace cg = cooperative_groups;

#define LSEQ   2048
#define DMODEL 256
#define NHALF  32
#define TMAX   1024
#define TM2    384
#define KPAD   16
#define KROWS  (LSEQ + 2*KPAD)
#define TT     16

typedef __attribute__((ext_vector_type(8))) short short8;
typedef __attribute__((ext_vector_type(4))) short short4v;
typedef __attribute__((ext_vector_type(4))) float f32x4;
typedef __attribute__((ext_vector_type(4))) unsigned int u32x4;

// ---- geometry (R13-R16-verified) ----------------------------------------
#define U3STR   2136
#define U3SH    (8*U3STR)                 // 17088 shorts per d
#define U3BYTES (U3SH*2)                  // 34176
#define KSLOT_STR 8848
#define OFF_K    U3BYTES
#define SMEM_ALL (OFF_K + 8*KSLOT_STR)    // 104960 dyn LDS (covers all phases)
#define KBF_SH  4400
#define YSWZ(r)  ((((r) >> 2) & 7) << 2)
// ---- ws layout (yT bf16)
#define UIMG_SHORTS ((size_t)DMODEL*U3SH)
#define KBF_OFF_SH  UIMG_SHORTS
#define YT_OFF_B    ((UIMG_SHORTS + (size_t)DMODEL*KBF_SH)*2)
#define WS_NEED3    (YT_OFF_B + (size_t)8*LSEQ*DMODEL*2)

// ---- prep-phase shared overlay (bytes, within sm[])
#define PB_CT0 0
#define PB_CT1 4928
#define PB_HRE 9856
#define PB_HIE 11392
#define PB_HIO 12160
#define PB_P   12928
#define PB_Q   17280
#define PB_C   23808

#define MF(a, b, c) __builtin_amdgcn_mfma_f32_16x16x32_bf16((a), (b), (c), 0, 0, 0)

#define BODY(P) do {                                                        \
    const short8 bcur = Bb[(P) & 3];                                        \
    Bb[((P)+2) & 3] = *(const short8*)(sm + aBn);                           \
    acc[7] = MF(A[((P)+1) & 7], bcur, acc[7]);                              \
    A[((P)+1) & 7] = *(const short8*)(sm + aAn);                            \
    aAn += 64; aBn += 64;                                                   \
    acc[6] = MF(A[((P)+2) & 7], bcur, acc[6]);                              \
    acc[5] = MF(A[((P)+3) & 7], bcur, acc[5]);                              \
    acc[4] = MF(A[((P)+4) & 7], bcur, acc[4]);                              \
    acc[3] = MF(A[((P)+5) & 7], bcur, acc[3]);                              \
    acc[2] = MF(A[((P)+6) & 7], bcur, acc[2]);                              \
    acc[1] = MF(A[((P)+7) & 7], bcur, acc[1]);                              \
    acc[0] = MF(A[(P) & 7],     bcur, acc[0]);                              \
} while (0)

// ============================================================ fused cooperative kernel:
// 256 blocks x 512 threads, 1 block/CU. Phase 1 = prep (transpose job +
// build job per block, verified R16 bodies). Phase 2 = verified R15 mfma9.
// Phase 3 = ytr (512-thread port). grid.sync() between phases.
__global__ __launch_bounds__(512, 1) void s4d_all(
    const float* __restrict__ u,
    const float* __restrict__ A_real, const float* __restrict__ A_imag,
    const float* __restrict__ C_real, const float* __restrict__ C_imag,
    const float* __restrict__ Dvec,
    unsigned short* __restrict__ uimg, unsigned short* __restrict__ kbf,
    unsigned short* __restrict__ yTb, float* __restrict__ out)
{
    extern __shared__ __align__(16) unsigned char sm[];
    cg::grid_group grid = cg::this_grid();
    const int tid = threadIdx.x;
    const int job = blockIdx.x;

    // ================= phase 1a: transpose job (m0, b) -> uimg
    {
        unsigned short (*tr)[66] = (unsigned short (*)[66])sm;
        const int jx = job & 31;
        const int m0 = jx * 64;
        const int b  = job >> 5;

        const int mmBase = tid >> 6;
        const int d4     = (tid & 63) * 4;
        #pragma unroll
        for (int it = 0; it < 8; ++it) {
            int mm = it*8 + mmBase;
            const float* src = u + ((size_t)b*LSEQ + m0 + mm)*DMODEL + d4;
            f32x4 v = *(const f32x4*)src;
            #pragma unroll
            for (int j = 0; j < 4; ++j) {
                __hip_bfloat16 hb = __float2bfloat16(v[j]);
                tr[d4+j][mm] = *(unsigned short*)&hb;
            }
        }
        __syncthreads();
        #pragma unroll
        for (int P = 0; P < 4; ++P) {
            int d = P*64 + (tid >> 3);
            int c = tid & 7;
            const unsigned short* s = &tr[d][c*8];
            u32x4 w = { *(const unsigned*)(s),   *(const unsigned*)(s+2),
                        *(const unsigned*)(s+4), *(const unsigned*)(s+6) };
            *(u32x4*)(uimg + (size_t)d*U3SH + (size_t)b*U3STR + 32 + m0 + c*8) = w;
        }
        if (jx == 0 && tid < 256) {
            int d = tid;
            #pragma unroll
            for (int c = 0; c < 4; ++c)
                *(u32x4*)(uimg + (size_t)d*U3SH + (size_t)b*U3STR + c*8) = (u32x4){0,0,0,0};
        } else if (jx == 31 && tid < 256) {
            int d = tid;
            #pragma unroll
            for (int c = 0; c < 7; ++c)
                *(u32x4*)(uimg + (size_t)d*U3SH + (size_t)b*U3STR + 2080 + c*8) = (u32x4){0,0,0,0};
        }
        __syncthreads();
    }

    // ================= phase 1b: build job d = job -> kbf (verified R15/R16 body)
    {
        const int d = job;
        float* ctL0 = (float*)(sm + PB_CT0);
        float* ctL1 = (float*)(sm + PB_CT1);
        float* hRe  = (float*)(sm + PB_HRE);
        float* hImE = (float*)(sm + PB_HIE);
        float* hImO = (float*)(sm + PB_HIO);
        float* Pp   = (float*)(sm + PB_P);
        float* Qp   = (float*)(sm + PB_Q);
        float* Cp   = (float*)(sm + PB_C);

        for (int i = tid; i < 1220; i += 512) {
            int x0 = (i - 196) & 2047;
            int x1 = (i - 195) & 2047;
            float a0 = (float)(M_PI/(2.0*(double)LSEQ)) * (float)(2*x0 + 1);
            float a1 = (float)(M_PI/(2.0*(double)LSEQ)) * (float)(2*x1 + 1);
            float s0, c0, s1, c1;
            sincosf(a0, &s0, &c0);
            sincosf(a1, &s1, &c1);
            ctL0[i] = c0 / s0;
            ctL1[i] = c1 / s1;
        }
        if (tid < 32) {
            const int n = tid;
            float ar = A_real[d*NHALF + n], ai = A_imag[d*NHALF + n];
            float cr = C_real[d*NHALF + n], ci = C_imag[d*NHALF + n];
            float amp = expf(-0.1f * expf(ar));
            float sn, cs; sincosf(0.1f * ai, &sn, &cs);
            float Adr = amp*cs, Adi = amp*sn;
            float pr = 1.f, pi = 0.f;
            Pp[n*2] = pr; Pp[n*2 + 1] = pi;
            #pragma unroll
            for (int i = 1; i < 16; ++i) {
                float nr = pr*Adr - pi*Adi;
                float ni = pr*Adi + pi*Adr;
                pr = nr; pi = ni;
                Pp[i*68 + n*2] = pr; Pp[i*68 + n*2 + 1] = pi;
            }
            float a16r = pr*Adr - pi*Adi;
            float a16i = pr*Adi + pi*Adr;
            float qr = 1.f, qi = 0.f;
            Qp[n*2] = qr; Qp[n*2 + 1] = qi;
            #pragma unroll
            for (int j = 1; j < 24; ++j) {
                float nr = qr*a16r - qi*a16i;
                float ni = qr*a16i + qi*a16r;
                qr = nr; qi = ni;
                Qp[j*68 + n*2] = qr; Qp[j*68 + n*2 + 1] = qi;
            }
            Cp[n*2] = cr; Cp[n*2 + 1] = ci;
        }
        __syncthreads();

        if (tid < TM2) {
            const int tau = tid, ii = tau & 15, jj = tau >> 4;
            const float* Pr = Pp + ii*68;
            const float* Qr = Qp + jj*68;
            float aR = 0.f, aI = 0.f;
            #pragma unroll 4
            for (int n = 0; n < 32; n += 2) {
                f32x4 p = *(const f32x4*)(Pr + 2*n);
                f32x4 q = *(const f32x4*)(Qr + 2*n);
                f32x4 c = *(const f32x4*)(Cp + 2*n);
                float w0r = p[0]*q[0] - p[1]*q[1];
                float w0i = p[0]*q[1] + p[1]*q[0];
                aR = fmaf(c[0], w0r, aR); aR = fmaf(-c[1], w0i, aR);
                aI = fmaf(c[0], w0i, aI); aI = fmaf( c[1], w0r, aI);
                float w1r = p[2]*q[2] - p[3]*q[3];
                float w1i = p[2]*q[3] + p[3]*q[2];
                aR = fmaf(c[2], w1r, aR); aR = fmaf(-c[3], w1i, aR);
                aI = fmaf(c[2], w1i, aI); aI = fmaf( c[3], w1r, aI);
            }
            hRe[tau] = aR;
            if (tau & 1) hImO[tau >> 1] = aI;
            else         hImE[tau >> 1] = aI;
        }
        __syncthreads();

        unsigned short* kd = kbf + (size_t)d*KBF_SH;
        {
            const int pt = tid & 1;
            const int g  = tid >> 1;
            float accs[4] = {0.f, 0.f, 0.f, 0.f};

            if (g < 128) {                    // only t < 1024 taps are kept
                const float* tb = pt ? ctL1 : ctL0;
                const float* hb = pt ? hImE : hImO;
                float acc0 = 0.f, acc1 = 0.f, acc2 = 0.f, acc3 = 0.f;
                int qb = 4*g + 192;
                f32x4 Wlo = *(const f32x4*)(tb + qb);
                f32x4 Whi = *(const f32x4*)(tb + qb + 4);

                #pragma unroll 4
                for (int R = 0; R < 48; ++R) {
                    f32x4 hv = *(const f32x4*)(hb + 4*R);
                    f32x4 Wn = *(const f32x4*)(tb + qb - 4);
                    acc0 = fmaf(Wlo[3], hv[0], acc0); acc1 = fmaf(Whi[0], hv[0], acc1);
                    acc2 = fmaf(Whi[1], hv[0], acc2); acc3 = fmaf(Whi[2], hv[0], acc3);
                    acc0 = fmaf(Wlo[2], hv[1], acc0); acc1 = fmaf(Wlo[3], hv[1], acc1);
                    acc2 = fmaf(Whi[0], hv[1], acc2); acc3 = fmaf(Whi[1], hv[1], acc3);
                    acc0 = fmaf(Wlo[1], hv[2], acc0); acc1 = fmaf(Wlo[2], hv[2], acc1);
                    acc2 = fmaf(Wlo[3], hv[2], acc2); acc3 = fmaf(Whi[0], hv[2], acc3);
                    acc0 = fmaf(Wlo[0], hv[3], acc0); acc1 = fmaf(Wlo[1], hv[3], acc1);
                    acc2 = fmaf(Wlo[2], hv[3], acc2); acc3 = fmaf(Wlo[3], hv[3], acc3);
                    Whi = Wlo; Wlo = Wn; qb -= 4;
                }
                accs[0] = acc0; accs[1] = acc1; accs[2] = acc2; accs[3] = acc3;
            }
            #pragma unroll
            for (int e = 0; e < 4; ++e) {
                int t = 8*g + 2*e + pt;
                unsigned short us = 0;
                if (t < 1024) {
                    float base = (t < TM2) ? hRe[t] : 0.f;
                    float kv = base - accs[e] * (1.0f/(float)LSEQ);
                    __hip_bfloat16 hbv = __float2bfloat16(kv);
                    us = *(unsigned short*)&hbv;
                }
                kd[1056 + t] = us;
            }
        }
        if (tid < 132) *(u32x4*)((unsigned char*)kd + tid*16) = (u32x4){0,0,0,0};
        if (tid < 162) *(u32x4*)((unsigned char*)kd + 6208 + tid*16) = (u32x4){0,0,0,0};
    }

    __threadfence();
    grid.sync();

    // ================= phase 2: mfma (verified R15 mfma9 body, d = swizzle(job))
    {
        const int d = ((job & 7) << 5) | (job >> 3);   // XCD-swizzle

        const u32x4* gu = (const u32x4*)(uimg + (size_t)d*U3SH);
        const u32x4* gk = (const u32x4*)(kbf + (size_t)d*KBF_SH);
        u32x4 stg[5], kst[2];
        #pragma unroll
        for (int r = 0; r < 5; ++r) {
            int i = tid + 512*r;
            if (i < U3SH/8) stg[r] = gu[i];
        }
        #pragma unroll
        for (int r = 0; r < 2; ++r) {
            int i = tid + 512*r;
            if (i < KBF_SH/8) kst[r] = gk[i];
        }
        #pragma unroll
        for (int r = 0; r < 2; ++r) {
            int i = tid + 512*r;
            if (i < KBF_SH/8) *(u32x4*)(sm + OFF_K + i*16) = kst[r];
        }
        __syncthreads();

        // expand: slots 1..7 from slot0
        {
            const unsigned short* s0p = (const unsigned short*)(sm + OFF_K);
            for (int i = tid; i < 548; i += 512) {
                int z0 = i*8;
                u32x4 va = *(const u32x4*)(s0p + z0);
                u32x4 vb = *(const u32x4*)(s0p + z0 + 8);
                unsigned src[8] = { va[0], va[1], va[2], va[3],
                                    vb[0], vb[1], vb[2], vb[3] };
                #pragma unroll
                for (int c = 1; c < 8; ++c) {
                    u32x4 w;
                    if ((c & 1) == 0) {
                        int q = c >> 1;
                        w = (u32x4){ src[q], src[q+1], src[q+2], src[q+3] };
                    } else {
                        int q = (c - 1) >> 1;
                        w = (u32x4){ (src[q]   >> 16) | (src[q+1] << 16),
                                     (src[q+1] >> 16) | (src[q+2] << 16),
                                     (src[q+2] >> 16) | (src[q+3] << 16),
                                     (src[q+3] >> 16) | (src[q+4] << 16) };
                    }
                    *(u32x4*)(sm + OFF_K + c*KSLOT_STR + z0*2) = w;
                }
            }
        }
        // commit u to LDS
        #pragma unroll
        for (int r = 0; r < 5; ++r) {
            int i = tid + 512*r;
            if (i < U3SH/8) *(u32x4*)(sm + i*16) = stg[r];
        }
        __syncthreads();

        const int lane = tid & 63, wv = tid >> 6;
        const int h    = lane >> 4;
        const int col  = lane & 15;
        const int t0w  = wv << 8;

        const int cA   = (7 - col) & 7;
        const int bA0  = OFF_K + cA*KSLOT_STR + 2*(2047 + 8*h - col - cA - t0w);
        const int laneB3 = (col & 7)*(U3STR*2) + 64 + 16*h + 32*(col >> 3);

        const int qs   = (wv > 4) ? 8*(wv - 4) : 0;
        const int nOut = (wv < 4) ? (wv + 1) : 5;

        const int bA0s = bA0 + 64*qs;
        const int lB3s = laneB3 + 64*qs;

        const float dv = Dvec[d];
        f32x4 acc[8];
        #pragma unroll
        for (int j = 0; j < 8; ++j) acc[j] = (f32x4){dv, dv, dv, dv};

        short8 A[8], Bb[4];
        #pragma unroll
        for (int w = 0; w < 8; ++w)
            A[w] = *(const short8*)(sm + bA0s - 64*((8 - w) & 7));
        Bb[0] = *(const short8*)(sm + lB3s - 64);
        Bb[1] = *(const short8*)(sm + lB3s);

        int aAn = bA0s + 64;
        int aBn = lB3s + 64;

        BODY(0);
        for (int o = 0; o < nOut; ++o) {
            BODY(1); BODY(2); BODY(3); BODY(4);
            BODY(5); BODY(6); BODY(7); BODY(0);
        }

        // epilogue: bf16x4 to yTb[d][b][t]
        {
            const int b    = col & 7;
            const int hi16 = (col >> 3) << 4;
            unsigned short* yb = yTb + (size_t)d*(8*LSEQ) + (size_t)b*LSEQ;
            #pragma unroll
            for (int j = 0; j < 8; ++j) {
                int trow = t0w + 32*j + hi16 + 4*h;
                short4v pk;
                #pragma unroll
                for (int e = 0; e < 4; ++e) {
                    __hip_bfloat16 hb = __float2bfloat16(acc[j][e]);
                    pk[e] = *(short*)&hb;
                }
                *(short4v*)(yb + trow) = pk;
            }
        }
    }

    __threadfence();
    grid.sync();

    // ================= phase 3: ytr (512-thread port of verified R13-R16 body)
    {
        float* tr2 = (float*)sm;                      // [64][260] + swizzle
        const int t0 = (job & 31) * 64;
        const int b  = job >> 5;

        const int g2 = tid >> 4, i = tid & 15;        // g2 0..31
        #pragma unroll
        for (int dp = 0; dp < 8; ++dp) {
            int dd = dp*32 + g2;
            short4v v = *(const short4v*)(yTb + (size_t)dd*(8*LSEQ) + (size_t)b*LSEQ + t0 + i*4);
            #pragma unroll
            for (int e = 0; e < 4; ++e) {
                int r = i*4 + e;
                unsigned uv = ((unsigned)(unsigned short)v[e]) << 16;
                tr2[(r*260 + dd) ^ YSWZ(r)] = *(float*)&uv;
            }
        }
        __syncthreads();
        const int d4 = (tid & 63)*4, ttB = tid >> 6;  // ttB 0..7
        #pragma unroll
        for (int s = 0; s < 8; ++s) {
            int tt = s*8 + ttB;
            f32x4 w = *(const f32x4*)(tr2 + ((tt*260 + d4) ^ YSWZ(tt)));
            *(f32x4*)(out + ((size_t)b*LSEQ + t0 + tt)*DMODEL + d4) = w;
        }
    }
}

// ============================================================ fallback (R1, verified)
__global__ __launch_bounds__(256) void s4d_build_k(
    const float* __restrict__ A_real, const float* __restrict__ A_imag,
    const float* __restrict__ C_real, const float* __restrict__ C_imag,
    float* __restrict__ kT)
{
    __shared__ float hRe[TMAX], hIm[TMAX], ct[LSEQ], prm[4][NHALF];
    const int tid = threadIdx.x;
    const int d   = blockIdx.x;
    if (tid < NHALF) {
        prm[0][tid] = A_real[d*NHALF + tid];
        prm[1][tid] = A_imag[d*NHALF + tid];
        prm[2][tid] = C_real[d*NHALF + tid];
        prm[3][tid] = C_imag[d*NHALF + tid];
    }
    #pragma unroll
    for (int r = 0; r < LSEQ/256; ++r) {
        int i = tid + 256*r;
        float ang = (float)(M_PI/(2.0*(double)LSEQ)) * (float)(2*i + 1);
        float sv, cv; sincosf(ang, &sv, &cv);
        ct[i] = cv / sv;
    }
    __syncthreads();
    for (int r = 0; r < TMAX/256; ++r) {
        int tau = tid + 256*r;
        float aR = 0.f, aI = 0.f;
        for (int n = 0; n < NHALF; ++n) {
            float lr  = -expf(prm[0][n]) * 0.1f;
            float amp = expf(lr * (float)tau);
            double ph = (double)prm[1][n] * 0.1 * (double)tau;
            ph -= floor(ph * (1.0/(2.0*M_PI))) * (2.0*M_PI);
            float sv, cv; sincosf((float)ph, &sv, &cv);
            float cr = prm[2][n], ci = prm[3][n];
            aR = fmaf(amp, cr*cv - ci*sv, aR);
            aI = fmaf(amp, cr*sv + ci*cv, aI);
        }
        hRe[tau] = aR; hIm[tau] = aI;
    }
    __syncthreads();
    float base[8], hsum[8];
    #pragma unroll
    for (int r = 0; r < 8; ++r) {
        base[r] = (r < 4) ? hRe[tid + 256*r] : 0.f;
        hsum[r] = 0.f;
    }
    const int tau0 = (tid & 1) ^ 1;
    for (int tau = tau0; tau < TMAX; tau += 2) {
        float him = hIm[tau];
        #pragma unroll
        for (int r = 0; r < 8; ++r) {
            int idx = ((tid + 256*r - tau) & (2*LSEQ - 1)) >> 1;
            hsum[r] = fmaf(ct[idx], him, hsum[r]);
        }
    }
    #pragma unroll
    for (int r = 0; r < 8; ++r) {
        int t = tid + 256*r;
        kT[(t + KPAD)*DMODEL + d] = base[r] - hsum[r] * (1.0f/(float)LSEQ);
    }
    if (tid < 2*KPAD) {
        int row = (tid < KPAD) ? tid : (LSEQ + KPAD + (tid - KPAD));
        kT[row*DMODEL + d] = 0.f;
    }
}

__global__ __launch_bounds__(256) void s4d_conv(
    const float* __restrict__ u, const float* __restrict__ Dvec,
    const float* __restrict__ kT, float* __restrict__ out)
{
    const int d  = threadIdx.x;
    const int t0 = blockIdx.x * TT;
    const int b  = blockIdx.y;
    float dvv = Dvec[d];
    float acc[TT];
    #pragma unroll
    for (int i = 0; i < TT; ++i) acc[i] = dvv;
    const float* ub   = u + (size_t)b * LSEQ * DMODEL + d;
    const float* kcol = kT + d;
    int mstart = t0 - 1024; if (mstart < 0) mstart = 0;
    int mend   = t0 + 1040; if (mend > LSEQ) mend = LSEQ;
    float kreg[31];
    {
        int jpb = mstart - t0 + 1024;
        #pragma unroll
        for (int r = 0; r < 31; ++r) kreg[r] = kcol[(jpb + r)*DMODEL];
    }
    for (int m0 = mstart; m0 < mend; m0 += TT) {
        float ureg[TT];
        #pragma unroll
        for (int mm = 0; mm < TT; ++mm) ureg[mm] = ub[(m0 + mm)*DMODEL];
        float knew[TT];
        if (m0 + TT < mend) {
            int jnb = m0 - t0 + 1024 + 31;
            #pragma unroll
            for (int r = 0; r < TT; ++r) knew[r] = kcol[(jnb + r)*DMODEL];
        } else {
            #pragma unroll
            for (int r = 0; r < TT; ++r) knew[r] = 0.f;
        }
        #pragma unroll
        for (int mm = 0; mm < TT; ++mm)
            #pragma unroll
            for (int tt = 0; tt < TT; ++tt)
                acc[tt] = fmaf(ureg[mm], kreg[mm - tt + 15], acc[tt]);
        #pragma unroll
        for (int r = 0; r < 15; ++r) kreg[r] = kreg[r + 16];
        #pragma unroll
        for (int r = 0; r < 16; ++r) kreg[15 + r] = knew[r];
    }
    float* ob = out + ((size_t)b * LSEQ + t0) * DMODEL + d;
    #pragma unroll
    for (int tt = 0; tt < TT; ++tt) ob[tt*DMODEL] = acc[tt];
}

// ============================================================ launch
extern "C" void kernel_launch(void* const* d_in, const int* in_sizes, int n_in,
                              void* d_out, int out_size, void* d_ws, size_t ws_size,
                              hipStream_t stream)
{
    const float* u  = (const float*)d_in[0];
    const float* Ar = (const float*)d_in[1];
    const float* Ai = (const float*)d_in[2];
    const float* Cr = (const float*)d_in[3];
    const float* Ci = (const float*)d_in[4];
    const float* Dv = (const float*)d_in[5];
    float* out = (float*)d_out;
    int B = in_sizes[0] / (LSEQ * DMODEL);

    if (B == 8 && ws_size >= WS_NEED3) {
        unsigned short* uimg = (unsigned short*)d_ws;
        unsigned short* kbf  = uimg + KBF_OFF_SH;
        unsigned short* yTb  = (unsigned short*)((unsigned char*)d_ws + YT_OFF_B);
        hipFuncSetAttribute((const void*)s4d_all,
                            hipFuncAttributeMaxDynamicSharedMemorySize, SMEM_ALL);
        void* args[] = { (void*)&u, (void*)&Ar, (void*)&Ai, (void*)&Cr, (void*)&Ci,
                         (void*)&Dv, (void*)&uimg, (void*)&kbf, (void*)&yTb, (void*)&out };
        hipLaunchCooperativeKernel((const void*)s4d_all, dim3(DMODEL), dim3(512),
                                   args, SMEM_ALL, stream);
    } else {
        float* kT = (float*)d_ws;
        s4d_build_k<<<DMODEL, 256, 0, stream>>>(Ar, Ai, Cr, Ci, kT);
        s4d_conv<<<dim3(LSEQ/TT, B), 256, 0, stream>>>(u, Dv, kT, out);
    }
}

// Round 18
// 32.239 us; speedup vs baseline: 6.4737x; 6.4737x over previous
//
#include <hip/hip_runtime.h>
#include <hip/hip_bf16.h>
#include <math.h>

#define LSEQ   2048
#define DMODEL 256
#define NHALF  32
#define TMAX   1024                 // fallback-path truncation
#define TM2    384                  // fast-path truncation
#define KPAD   16
#define KROWS  (LSEQ + 2*KPAD)
#define TT     16

typedef __attribute__((ext_vector_type(8))) short short8;
typedef __attribute__((ext_vector_type(4))) short short4v;
typedef __attribute__((ext_vector_type(4))) float f32x4;
typedef __attribute__((ext_vector_type(4))) unsigned int u32x4;

// ---- hi-packed MFMA geometry (R9-R15-verified addressing) ----------------
#define U3STR   2136
#define U3SH    (8*U3STR)                 // 17088 shorts per d
#define U3BYTES (U3SH*2)                  // 34176
#define KSLOT_STR 8848
#define OFF_K    U3BYTES
#define SMEM_F3  (OFF_K + 8*KSLOT_STR)    // 104960 dyn LDS for mfma kernel
#define KBF_SH   4400
#define YTR_SMEM (64*260*4)               // 66560 dyn LDS for ytr
#define YSWZ(r)  ((((r) >> 2) & 7) << 2)
// ---- ws layout (yT bf16)
#define UIMG_SHORTS ((size_t)DMODEL*U3SH)
#define KBF_OFF_SH  UIMG_SHORTS
#define YT_OFF_B    ((UIMG_SHORTS + (size_t)DMODEL*KBF_SH)*2)
#define WS_NEED3    (YT_OFF_B + (size_t)8*LSEQ*DMODEL*2)

// ---- prep kernel shared-buffer overlay (bytes)
#define PB_CT0 0
#define PB_CT1 4928
#define PB_HRE 9856
#define PB_HIE 11392
#define PB_HIO 12160
#define PB_P   12928
#define PB_Q   17280
#define PB_C   23808
#define PB_BYTES 33792

// ============================================================ prep kernel:
// R10-R15-verified; taps j >= 1024 zeroed (triangular kernel).
__global__ __launch_bounds__(512, 2) void s4d_prep(
    const float* __restrict__ u,
    const float* __restrict__ A_real, const float* __restrict__ A_imag,
    const float* __restrict__ C_real, const float* __restrict__ C_imag,
    unsigned short* __restrict__ uimg, unsigned short* __restrict__ kbf)
{
    __shared__ __align__(16) unsigned char pbuf[PB_BYTES];
    const int tid = threadIdx.x;

    if (blockIdx.y < 8) {
        unsigned short (*tr)[66] = (unsigned short (*)[66])pbuf;
        const int m0 = blockIdx.x * 64;
        const int b  = blockIdx.y;

        const int mmBase = tid >> 6;
        const int d4     = (tid & 63) * 4;
        #pragma unroll
        for (int it = 0; it < 8; ++it) {
            int mm = it*8 + mmBase;
            const float* src = u + ((size_t)b*LSEQ + m0 + mm)*DMODEL + d4;
            f32x4 v = *(const f32x4*)src;
            #pragma unroll
            for (int j = 0; j < 4; ++j) {
                __hip_bfloat16 hb = __float2bfloat16(v[j]);
                tr[d4+j][mm] = *(unsigned short*)&hb;
            }
        }
        __syncthreads();
        #pragma unroll
        for (int P = 0; P < 4; ++P) {
            int d = P*64 + (tid >> 3);
            int c = tid & 7;
            const unsigned short* s = &tr[d][c*8];
            u32x4 w = { *(const unsigned*)(s),   *(const unsigned*)(s+2),
                        *(const unsigned*)(s+4), *(const unsigned*)(s+6) };
            *(u32x4*)(uimg + (size_t)d*U3SH + (size_t)b*U3STR + 32 + m0 + c*8) = w;
        }
        if (blockIdx.x == 0 && tid < 256) {
            int d = tid;
            #pragma unroll
            for (int c = 0; c < 4; ++c)
                *(u32x4*)(uimg + (size_t)d*U3SH + (size_t)b*U3STR + c*8) = (u32x4){0,0,0,0};
        } else if (blockIdx.x == 31 && tid < 256) {
            int d = tid;
            #pragma unroll
            for (int c = 0; c < 7; ++c)
                *(u32x4*)(uimg + (size_t)d*U3SH + (size_t)b*U3STR + 2080 + c*8) = (u32x4){0,0,0,0};
        }
    } else {
        const int d = (blockIdx.y - 8)*32 + blockIdx.x;
        float* ctL0 = (float*)(pbuf + PB_CT0);
        float* ctL1 = (float*)(pbuf + PB_CT1);
        float* hRe  = (float*)(pbuf + PB_HRE);
        float* hImE = (float*)(pbuf + PB_HIE);
        float* hImO = (float*)(pbuf + PB_HIO);
        float* Pp   = (float*)(pbuf + PB_P);
        float* Qp   = (float*)(pbuf + PB_Q);
        float* Cp   = (float*)(pbuf + PB_C);

        for (int i = tid; i < 1220; i += 512) {
            int x0 = (i - 196) & 2047;
            int x1 = (i - 195) & 2047;
            float a0 = (float)(M_PI/(2.0*(double)LSEQ)) * (float)(2*x0 + 1);
            float a1 = (float)(M_PI/(2.0*(double)LSEQ)) * (float)(2*x1 + 1);
            float s0, c0, s1, c1;
            sincosf(a0, &s0, &c0);
            sincosf(a1, &s1, &c1);
            ctL0[i] = c0 / s0;
            ctL1[i] = c1 / s1;
        }
        if (tid < 32) {
            const int n = tid;
            float ar = A_real[d*NHALF + n], ai = A_imag[d*NHALF + n];
            float cr = C_real[d*NHALF + n], ci = C_imag[d*NHALF + n];
            float amp = expf(-0.1f * expf(ar));
            float sn, cs; sincosf(0.1f * ai, &sn, &cs);
            float Adr = amp*cs, Adi = amp*sn;
            float pr = 1.f, pi = 0.f;
            Pp[n*2] = pr; Pp[n*2 + 1] = pi;
            #pragma unroll
            for (int i = 1; i < 16; ++i) {
                float nr = pr*Adr - pi*Adi;
                float ni = pr*Adi + pi*Adr;
                pr = nr; pi = ni;
                Pp[i*68 + n*2] = pr; Pp[i*68 + n*2 + 1] = pi;
            }
            float a16r = pr*Adr - pi*Adi;
            float a16i = pr*Adi + pi*Adr;
            float qr = 1.f, qi = 0.f;
            Qp[n*2] = qr; Qp[n*2 + 1] = qi;
            #pragma unroll
            for (int j = 1; j < 24; ++j) {
                float nr = qr*a16r - qi*a16i;
                float ni = qr*a16i + qi*a16r;
                qr = nr; qi = ni;
                Qp[j*68 + n*2] = qr; Qp[j*68 + n*2 + 1] = qi;
            }
            Cp[n*2] = cr; Cp[n*2 + 1] = ci;
        }
        __syncthreads();

        if (tid < TM2) {
            const int tau = tid, ii = tau & 15, jj = tau >> 4;
            const float* Pr = Pp + ii*68;
            const float* Qr = Qp + jj*68;
            float aR = 0.f, aI = 0.f;
            #pragma unroll 4
            for (int n = 0; n < 32; n += 2) {
                f32x4 p = *(const f32x4*)(Pr + 2*n);
                f32x4 q = *(const f32x4*)(Qr + 2*n);
                f32x4 c = *(const f32x4*)(Cp + 2*n);
                float w0r = p[0]*q[0] - p[1]*q[1];
                float w0i = p[0]*q[1] + p[1]*q[0];
                aR = fmaf(c[0], w0r, aR); aR = fmaf(-c[1], w0i, aR);
                aI = fmaf(c[0], w0i, aI); aI = fmaf( c[1], w0r, aI);
                float w1r = p[2]*q[2] - p[3]*q[3];
                float w1i = p[2]*q[3] + p[3]*q[2];
                aR = fmaf(c[2], w1r, aR); aR = fmaf(-c[3], w1i, aR);
                aI = fmaf(c[2], w1i, aI); aI = fmaf( c[3], w1r, aI);
            }
            hRe[tau] = aR;
            if (tau & 1) hImO[tau >> 1] = aI;
            else         hImE[tau >> 1] = aI;
        }
        __syncthreads();

        unsigned short* kd = kbf + (size_t)d*KBF_SH;
        {
            const int pt = tid & 1;
            const int g  = tid >> 1;
            float accs[4] = {0.f, 0.f, 0.f, 0.f};

            if (g < 128) {                    // only t < 1024 taps are kept
                const float* tb = pt ? ctL1 : ctL0;
                const float* hb = pt ? hImE : hImO;
                float acc0 = 0.f, acc1 = 0.f, acc2 = 0.f, acc3 = 0.f;
                int qb = 4*g + 192;
                f32x4 Wlo = *(const f32x4*)(tb + qb);
                f32x4 Whi = *(const f32x4*)(tb + qb + 4);

                #pragma unroll 4
                for (int R = 0; R < 48; ++R) {
                    f32x4 hv = *(const f32x4*)(hb + 4*R);
                    f32x4 Wn = *(const f32x4*)(tb + qb - 4);
                    acc0 = fmaf(Wlo[3], hv[0], acc0); acc1 = fmaf(Whi[0], hv[0], acc1);
                    acc2 = fmaf(Whi[1], hv[0], acc2); acc3 = fmaf(Whi[2], hv[0], acc3);
                    acc0 = fmaf(Wlo[2], hv[1], acc0); acc1 = fmaf(Wlo[3], hv[1], acc1);
                    acc2 = fmaf(Whi[0], hv[1], acc2); acc3 = fmaf(Whi[1], hv[1], acc3);
                    acc0 = fmaf(Wlo[1], hv[2], acc0); acc1 = fmaf(Wlo[2], hv[2], acc1);
                    acc2 = fmaf(Wlo[3], hv[2], acc2); acc3 = fmaf(Whi[0], hv[2], acc3);
                    acc0 = fmaf(Wlo[0], hv[3], acc0); acc1 = fmaf(Wlo[1], hv[3], acc1);
                    acc2 = fmaf(Wlo[2], hv[3], acc2); acc3 = fmaf(Wlo[3], hv[3], acc3);
                    Whi = Wlo; Wlo = Wn; qb -= 4;
                }
                accs[0] = acc0; accs[1] = acc1; accs[2] = acc2; accs[3] = acc3;
            }
            #pragma unroll
            for (int e = 0; e < 4; ++e) {
                int t = 8*g + 2*e + pt;
                unsigned short us = 0;
                if (t < 1024) {
                    float base = (t < TM2) ? hRe[t] : 0.f;
                    float kv = base - accs[e] * (1.0f/(float)LSEQ);
                    __hip_bfloat16 hbv = __float2bfloat16(kv);
                    us = *(unsigned short*)&hbv;
                }
                kd[1056 + t] = us;
            }
        }
        if (tid < 132) *(u32x4*)((unsigned char*)kd + tid*16) = (u32x4){0,0,0,0};
        if (tid < 162) *(u32x4*)((unsigned char*)kd + 6208 + tid*16) = (u32x4){0,0,0,0};
    }
}

// ============================================================ mfma kernel:
// R11-R15-verified structure with lower-triangular body windows.
#define MF(a, b, c) __builtin_amdgcn_mfma_f32_16x16x32_bf16((a), (b), (c), 0, 0, 0)

#define BODY(P) do {                                                        \
    const short8 bcur = Bb[(P) & 3];                                        \
    Bb[((P)+2) & 3] = *(const short8*)(sm + aBn);                           \
    acc[7] = MF(A[((P)+1) & 7], bcur, acc[7]);                              \
    A[((P)+1) & 7] = *(const short8*)(sm + aAn);                            \
    aAn += 64; aBn += 64;                                                   \
    acc[6] = MF(A[((P)+2) & 7], bcur, acc[6]);                              \
    acc[5] = MF(A[((P)+3) & 7], bcur, acc[5]);                              \
    acc[4] = MF(A[((P)+4) & 7], bcur, acc[4]);                              \
    acc[3] = MF(A[((P)+5) & 7], bcur, acc[3]);                              \
    acc[2] = MF(A[((P)+6) & 7], bcur, acc[2]);                              \
    acc[1] = MF(A[((P)+7) & 7], bcur, acc[1]);                              \
    acc[0] = MF(A[(P) & 7],     bcur, acc[0]);                              \
} while (0)

__global__ __launch_bounds__(512, 1) void s4d_mfma9(
    const unsigned short* __restrict__ uimg, const unsigned short* __restrict__ kbf,
    const float* __restrict__ Dvec, unsigned short* __restrict__ yTb)
{
    extern __shared__ __align__(16) unsigned char sm[];
    const int tid = threadIdx.x;
    const int Bk  = blockIdx.x;
    const int d   = ((Bk & 7) << 5) | (Bk >> 3);   // XCD-swizzle

    // ---- issue ALL global loads early; commit kbf now, u after expand (T14)
    const u32x4* gu = (const u32x4*)(uimg + (size_t)d*U3SH);
    const u32x4* gk = (const u32x4*)(kbf + (size_t)d*KBF_SH);
    u32x4 stg[5], kst[2];
    #pragma unroll
    for (int r = 0; r < 5; ++r) {
        int i = tid + 512*r;
        if (i < U3SH/8) stg[r] = gu[i];
    }
    #pragma unroll
    for (int r = 0; r < 2; ++r) {
        int i = tid + 512*r;
        if (i < KBF_SH/8) kst[r] = gk[i];
    }
    #pragma unroll
    for (int r = 0; r < 2; ++r) {
        int i = tid + 512*r;
        if (i < KBF_SH/8) *(u32x4*)(sm + OFF_K + i*16) = kst[r];
    }
    __syncthreads();

    // ---- expand: slots 1..7 from slot0 (verified R9-R15)
    {
        const unsigned short* s0p = (const unsigned short*)(sm + OFF_K);
        for (int i = tid; i < 548; i += 512) {
            int z0 = i*8;
            u32x4 va = *(const u32x4*)(s0p + z0);
            u32x4 vb = *(const u32x4*)(s0p + z0 + 8);
            unsigned src[8] = { va[0], va[1], va[2], va[3],
                                vb[0], vb[1], vb[2], vb[3] };
            #pragma unroll
            for (int c = 1; c < 8; ++c) {
                u32x4 w;
                if ((c & 1) == 0) {
                    int q = c >> 1;
                    w = (u32x4){ src[q], src[q+1], src[q+2], src[q+3] };
                } else {
                    int q = (c - 1) >> 1;
                    w = (u32x4){ (src[q]   >> 16) | (src[q+1] << 16),
                                 (src[q+1] >> 16) | (src[q+2] << 16),
                                 (src[q+2] >> 16) | (src[q+3] << 16),
                                 (src[q+3] >> 16) | (src[q+4] << 16) };
                }
                *(u32x4*)(sm + OFF_K + c*KSLOT_STR + z0*2) = w;
            }
        }
    }
    // ---- commit u to LDS (loads had expand-time to land)
    #pragma unroll
    for (int r = 0; r < 5; ++r) {
        int i = tid + 512*r;
        if (i < U3SH/8) *(u32x4*)(sm + i*16) = stg[r];
    }
    __syncthreads();

    // ---- main loop (addressing byte-identical; per-wave triangular window)
    const int lane = tid & 63, wv = tid >> 6;
    const int h    = lane >> 4;
    const int col  = lane & 15;
    const int t0w  = wv << 8;

    const int cA   = (7 - col) & 7;
    const int bA0  = OFF_K + cA*KSLOT_STR + 2*(2047 + 8*h - col - cA - t0w);
    const int laneB3 = (col & 7)*(U3STR*2) + 64 + 16*h + 32*(col >> 3);

    const int qs   = (wv > 4) ? 8*(wv - 4) : 0;   // start body (multiple of 8)
    const int nOut = (wv < 4) ? (wv + 1) : 5;     // outer 8-body iterations

    const int bA0s = bA0 + 64*qs;
    const int lB3s = laneB3 + 64*qs;

    const float dv = Dvec[d];
    f32x4 acc[8];
    #pragma unroll
    for (int j = 0; j < 8; ++j) acc[j] = (f32x4){dv, dv, dv, dv};

    short8 A[8], Bb[4];
    #pragma unroll
    for (int w = 0; w < 8; ++w)
        A[w] = *(const short8*)(sm + bA0s - 64*((8 - w) & 7));
    Bb[0] = *(const short8*)(sm + lB3s - 64);   // body qs
    Bb[1] = *(const short8*)(sm + lB3s);        // body qs+1

    int aAn = bA0s + 64;
    int aBn = lB3s + 64;                        // next load: body qs+2

    BODY(0);
    for (int o = 0; o < nOut; ++o) {
        BODY(1); BODY(2); BODY(3); BODY(4);
        BODY(5); BODY(6); BODY(7); BODY(0);
    }

    // ---- epilogue: bf16x4 (8B) to yTb[d][b][t]
    {
        const int b    = col & 7;
        const int hi16 = (col >> 3) << 4;
        unsigned short* yb = yTb + (size_t)d*(8*LSEQ) + (size_t)b*LSEQ;
        #pragma unroll
        for (int j = 0; j < 8; ++j) {
            int trow = t0w + 32*j + hi16 + 4*h;
            short4v pk;
            #pragma unroll
            for (int e = 0; e < 4; ++e) {
                __hip_bfloat16 hb = __float2bfloat16(acc[j][e]);
                pk[e] = *(short*)&hb;
            }
            *(short4v*)(yb + trow) = pk;
        }
    }
}

// ============================================================ yTb (bf16) -> out transpose
__global__ __launch_bounds__(256) void s4d_ytr(const unsigned short* __restrict__ yTb,
                                               float* __restrict__ out)
{
    extern __shared__ float tr2[];                // [64][260] + swizzle
    const int tid = threadIdx.x;
    const int t0  = blockIdx.x * 64;
    const int b   = blockIdx.y;

    const int g = tid >> 4, i = tid & 15;
    #pragma unroll
    for (int dp = 0; dp < 16; ++dp) {
        int dd = dp*16 + g;
        short4v v = *(const short4v*)(yTb + (size_t)dd*(8*LSEQ) + (size_t)b*LSEQ + t0 + i*4);
        #pragma unroll
        for (int e = 0; e < 4; ++e) {
            int r = i*4 + e;
            unsigned uv = ((unsigned)(unsigned short)v[e]) << 16;
            tr2[(r*260 + dd) ^ YSWZ(r)] = *(float*)&uv;
        }
    }
    __syncthreads();
    const int d4 = (tid & 63)*4, ttB = tid >> 6;
    #pragma unroll
    for (int s = 0; s < 16; ++s) {
        int tt = s*4 + ttB;
        f32x4 w = *(const f32x4*)(tr2 + ((tt*260 + d4) ^ YSWZ(tt)));
        *(f32x4*)(out + ((size_t)b*LSEQ + t0 + tt)*DMODEL + d4) = w;
    }
}

// ============================================================ fallback (R1, verified)
__global__ __launch_bounds__(256) void s4d_build_k(
    const float* __restrict__ A_real, const float* __restrict__ A_imag,
    const float* __restrict__ C_real, const float* __restrict__ C_imag,
    float* __restrict__ kT)
{
    __shared__ float hRe[TMAX], hIm[TMAX], ct[LSEQ], prm[4][NHALF];
    const int tid = threadIdx.x;
    const int d   = blockIdx.x;
    if (tid < NHALF) {
        prm[0][tid] = A_real[d*NHALF + tid];
        prm[1][tid] = A_imag[d*NHALF + tid];
        prm[2][tid] = C_real[d*NHALF + tid];
        prm[3][tid] = C_imag[d*NHALF + tid];
    }
    #pragma unroll
    for (int r = 0; r < LSEQ/256; ++r) {
        int i = tid + 256*r;
        float ang = (float)(M_PI/(2.0*(double)LSEQ)) * (float)(2*i + 1);
        float sv, cv; sincosf(ang, &sv, &cv);
        ct[i] = cv / sv;
    }
    __syncthreads();
    for (int r = 0; r < TMAX/256; ++r) {
        int tau = tid + 256*r;
        float aR = 0.f, aI = 0.f;
        for (int n = 0; n < NHALF; ++n) {
            float lr  = -expf(prm[0][n]) * 0.1f;
            float amp = expf(lr * (float)tau);
            double ph = (double)prm[1][n] * 0.1 * (double)tau;
            ph -= floor(ph * (1.0/(2.0*M_PI))) * (2.0*M_PI);
            float sv, cv; sincosf((float)ph, &sv, &cv);
            float cr = prm[2][n], ci = prm[3][n];
            aR = fmaf(amp, cr*cv - ci*sv, aR);
            aI = fmaf(amp, cr*sv + ci*cv, aI);
        }
        hRe[tau] = aR; hIm[tau] = aI;
    }
    __syncthreads();
    float base[8], hsum[8];
    #pragma unroll
    for (int r = 0; r < 8; ++r) {
        base[r] = (r < 4) ? hRe[tid + 256*r] : 0.f;
        hsum[r] = 0.f;
    }
    const int tau0 = (tid & 1) ^ 1;
    for (int tau = tau0; tau < TMAX; tau += 2) {
        float him = hIm[tau];
        #pragma unroll
        for (int r = 0; r < 8; ++r) {
            int idx = ((tid + 256*r - tau) & (2*LSEQ - 1)) >> 1;
            hsum[r] = fmaf(ct[idx], him, hsum[r]);
        }
    }
    #pragma unroll
    for (int r = 0; r < 8; ++r) {
        int t = tid + 256*r;
        kT[(t + KPAD)*DMODEL + d] = base[r] - hsum[r] * (1.0f/(float)LSEQ);
    }
    if (tid < 2*KPAD) {
        int row = (tid < KPAD) ? tid : (LSEQ + KPAD + (tid - KPAD));
        kT[row*DMODEL + d] = 0.f;
    }
}

__global__ __launch_bounds__(256) void s4d_conv(
    const float* __restrict__ u, const float* __restrict__ Dvec,
    const float* __restrict__ kT, float* __restrict__ out)
{
    const int d  = threadIdx.x;
    const int t0 = blockIdx.x * TT;
    const int b  = blockIdx.y;
    float dvv = Dvec[d];
    float acc[TT];
    #pragma unroll
    for (int i = 0; i < TT; ++i) acc[i] = dvv;
    const float* ub   = u + (size_t)b * LSEQ * DMODEL + d;
    const float* kcol = kT + d;
    int mstart = t0 - 1024; if (mstart < 0) mstart = 0;
    int mend   = t0 + 1040; if (mend > LSEQ) mend = LSEQ;
    float kreg[31];
    {
        int jpb = mstart - t0 + 1024;
        #pragma unroll
        for (int r = 0; r < 31; ++r) kreg[r] = kcol[(jpb + r)*DMODEL];
    }
    for (int m0 = mstart; m0 < mend; m0 += TT) {
        float ureg[TT];
        #pragma unroll
        for (int mm = 0; mm < TT; ++mm) ureg[mm] = ub[(m0 + mm)*DMODEL];
        float knew[TT];
        if (m0 + TT < mend) {
            int jnb = m0 - t0 + 1024 + 31;
            #pragma unroll
            for (int r = 0; r < TT; ++r) knew[r] = kcol[(jnb + r)*DMODEL];
        } else {
            #pragma unroll
            for (int r = 0; r < TT; ++r) knew[r] = 0.f;
        }
        #pragma unroll
        for (int mm = 0; mm < TT; ++mm)
            #pragma unroll
            for (int tt = 0; tt < TT; ++tt)
                acc[tt] = fmaf(ureg[mm], kreg[mm - tt + 15], acc[tt]);
        #pragma unroll
        for (int r = 0; r < 15; ++r) kreg[r] = kreg[r + 16];
        #pragma unroll
        for (int r = 0; r < 16; ++r) kreg[15 + r] = knew[r];
    }
    float* ob = out + ((size_t)b * LSEQ + t0) * DMODEL + d;
    #pragma unroll
    for (int tt = 0; tt < TT; ++tt) ob[tt*DMODEL] = acc[tt];
}

// ============================================================ launch
extern "C" void kernel_launch(void* const* d_in, const int* in_sizes, int n_in,
                              void* d_out, int out_size, void* d_ws, size_t ws_size,
                              hipStream_t stream)
{
    const float* u  = (const float*)d_in[0];
    const float* Ar = (const float*)d_in[1];
    const float* Ai = (const float*)d_in[2];
    const float* Cr = (const float*)d_in[3];
    const float* Ci = (const float*)d_in[4];
    const float* Dv = (const float*)d_in[5];
    float* out = (float*)d_out;
    int B = in_sizes[0] / (LSEQ * DMODEL);

    if (B == 8 && ws_size >= WS_NEED3) {
        unsigned short* uimg = (unsigned short*)d_ws;
        unsigned short* kbf  = uimg + KBF_OFF_SH;
        unsigned short* yTb  = (unsigned short*)((unsigned char*)d_ws + YT_OFF_B);
        hipFuncSetAttribute((const void*)s4d_mfma9,
                            hipFuncAttributeMaxDynamicSharedMemorySize, SMEM_F3);
        hipFuncSetAttribute((const void*)s4d_ytr,
                            hipFuncAttributeMaxDynamicSharedMemorySize, YTR_SMEM);
        s4d_prep<<<dim3(32, 16), 512, 0, stream>>>(u, Ar, Ai, Cr, Ci, uimg, kbf);
        s4d_mfma9<<<DMODEL, 512, SMEM_F3, stream>>>(uimg, kbf, Dv, yTb);
        s4d_ytr<<<dim3(LSEQ/64, 8), 256, YTR_SMEM, stream>>>(yTb, out);
    } else {
        float* kT = (float*)d_ws;
        s4d_build_k<<<DMODEL, 256, 0, stream>>>(Ar, Ai, Cr, Ci, kT);
        s4d_conv<<<dim3(LSEQ/TT, B), 256, 0, stream>>>(u, Dv, kT, out);
    }
}